// Round 3
// baseline (619.256 us; speedup 1.0000x reference)
//
#include <hip/hip_runtime.h>
#include <math.h>

#define BB 64
#define TT 1024
#define KK 128
#define START_TAG 126
#define STOP_TAG 127
#define NTHREADS 256   // 4 waves; thread: j = tid>>1 (row 0..127), h = tid&1 (k-half)
#define CS 64          // timesteps of F staged per chunk (32 KB LDS)

typedef float v2f __attribute__((ext_vector_type(2)));

// One barrier per step. Lane pair (j, h): dot-partial over 64 k's (32 pk_fma)
// plus e-sum partial (32 pk_add); one shfl_xor(1) level completes both the
// 128-wide dot d_j and the normalizer s = sum_k e_k in-wave. Ping-pong e
// buffers remove the WAR hazard (read cur, write cur^1), so the only
// cross-wave sync is the barrier that publishes the new e.
__global__ __launch_bounds__(NTHREADS) void crf_forward(
    const float* __restrict__ feats,   // [B,T,K]
    const int*   __restrict__ tags,    // [B,T]
    const int*   __restrict__ lens,    // [B]
    const float* __restrict__ trans,   // [K,K]
    float*       __restrict__ out_pb)  // [B]: forward_score - gold_score
{
  __shared__ float Tld[KK][KK + 1];               // raw transitions; reused by gold
  __shared__ __align__(16) float e_two[2][KK];    // ping-pong normalized alpha
  __shared__ __align__(16) float maxT_lds[KK];
  __shared__ __align__(16) float Fbuf[CS * KK];   // 32 KB chunk of F = exp(feat+maxT)
  __shared__ float wsum[NTHREADS / 64];

  const int tid = threadIdx.x;
  const int b   = blockIdx.x;
  const int j   = tid >> 1;                       // row 0..127
  const int h   = tid & 1;                        // k in [64h, 64h+64)
  const int L   = lens[b];
  const float* fb = feats + (size_t)b * TT * KK;

  // ---- stage transitions into LDS ----
  for (int i = tid; i < KK * KK; i += NTHREADS)
    Tld[i >> 7][i & (KK - 1)] = trans[i];
  __syncthreads();

  // ---- row max via half-max + one shfl; E row-half into registers ----
  float mT = -INFINITY;
  #pragma unroll
  for (int i = 0; i < 64; ++i) mT = fmaxf(mT, Tld[j][h * 64 + i]);
  mT = fmaxf(mT, __shfl_xor(mT, 1, 64));
  v2f Er2[32];
  #pragma unroll
  for (int i = 0; i < 32; ++i) {
    Er2[i][0] = __expf(Tld[j][h * 64 + 2 * i]     - mT);
    Er2[i][1] = __expf(Tld[j][h * 64 + 2 * i + 1] - mT);
  }
  if (h == 0) maxT_lds[j] = mT;

  // ---- init: e0 = onehot(START) in buffer 0; M0 = feats[b,0,START] ----
  if (tid < KK) e_two[0][tid] = (tid == START_TAG) ? 1.0f : 0.0f;
  float M = fb[START_TAG];
  __syncthreads();                                // maxT_lds + e visible

  // conversion maxT slice: thread's float4 covers columns (4*tid)&127
  const float4 mTv = ((const float4*)maxT_lds)[tid & 31];

  // ---- prefetch chunk 0 feats (32 floats/thread, fully coalesced) ----
  float4 pf[8];
  {
    const float4* src = (const float4*)fb;
    #pragma unroll
    for (int i = 0; i < 8; ++i) pf[i] = src[i * NTHREADS + tid];
  }

  int cur = 0;
  for (int c = 0; c * CS < L; ++c) {
    // convert prefetched feats -> F = exp(feat + maxT), coalesced float4 writes
    float4* Fb4 = (float4*)Fbuf;
    #pragma unroll
    for (int i = 0; i < 8; ++i) {
      float4 v = pf[i];
      float4 o;
      o.x = __expf(v.x + mTv.x); o.y = __expf(v.y + mTv.y);
      o.z = __expf(v.z + mTv.z); o.w = __expf(v.w + mTv.w);
      Fb4[i * NTHREADS + tid] = o;
    }
    // issue prefetch for chunk c+1 (latency hidden across 64 steps)
    if ((c + 1) * CS < TT) {
      const float4* src = (const float4*)(fb + (size_t)(c + 1) * CS * KK);
      #pragma unroll
      for (int i = 0; i < 8; ++i) pf[i] = src[i * NTHREADS + tid];
    }
    __syncthreads();                              // Fbuf visible

    const int t0 = (c == 0) ? 1 : c * CS;
    const int t1 = (L < (c + 1) * CS) ? L : (c + 1) * CS;
    for (int t = t0; t < t1; ++t) {
      const v2f* e2 = (const v2f*)(e_two[cur] + h * 64);
      v2f a0 = {0.f,0.f}, a1 = {0.f,0.f}, a2 = {0.f,0.f}, a3 = {0.f,0.f};
      v2f s0 = {0.f,0.f}, s1 = {0.f,0.f}, s2 = {0.f,0.f}, s3 = {0.f,0.f};
      #pragma unroll
      for (int i = 0; i < 8; ++i) {
        v2f ev0 = e2[4 * i + 0], ev1 = e2[4 * i + 1];
        v2f ev2 = e2[4 * i + 2], ev3 = e2[4 * i + 3];
        a0 += ev0 * Er2[4 * i + 0];  s0 += ev0;
        a1 += ev1 * Er2[4 * i + 1];  s1 += ev1;
        a2 += ev2 * Er2[4 * i + 2];  s2 += ev2;
        a3 += ev3 * Er2[4 * i + 3];  s3 += ev3;
      }
      v2f av = (a0 + a1) + (a2 + a3);
      v2f sv = (s0 + s1) + (s2 + s3);
      float p  = av[0] + av[1];
      float sg = sv[0] + sv[1];
      float F  = Fbuf[(t & (CS - 1)) * KK + j];   // off-chain (Fbuf stable)
      p  += __shfl_xor(p, 1, 64);                 // full dot d_j (both lanes)
      sg += __shfl_xor(sg, 1, 64);                // full s (both lanes)
      float r;
      asm("v_rcp_f32 %0, %1" : "=v"(r) : "v"(sg));
      if (h == 0) e_two[cur ^ 1][j] = p * F * r;
      if (tid < 64) M += __logf(sg);              // wave 0 only; used at the end
      cur ^= 1;
      __syncthreads();                            // publish new e
    }
  }

  // ---- terminal: fwd = M + log(sum_k e_k), wave 0 ----
  float fwd = 0.f;
  if (tid < 64) {
    float sm = e_two[cur][tid] + e_two[cur][tid + 64];
    #pragma unroll
    for (int m = 1; m < 64; m <<= 1) sm += __shfl_xor(sm, m, 64);
    fwd = M + __logf(sm);
  }

  // ---- gold score (all threads; Tld still holds raw transitions) ----
  float g = 0.f;
  const int* tg = tags + b * TT;
  for (int t = tid; t < TT; t += NTHREADS) {
    if (t < L)     g += fb[(size_t)t * KK + tg[t]];
    if (t < L - 1) g += Tld[tg[t + 1]][tg[t]];
  }
  #pragma unroll
  for (int m = 1; m < 64; m <<= 1) g += __shfl_xor(g, m, 64);
  if ((tid & 63) == 0) wsum[tid >> 6] = g;
  __syncthreads();
  if (tid == 0) {
    float gold = 0.f;
    #pragma unroll
    for (int w = 0; w < NTHREADS / 64; ++w) gold += wsum[w];
    out_pb[b] = fwd - gold;
  }
}

__global__ void crf_mean(const float* __restrict__ pb, float* __restrict__ out) {
  int tid = threadIdx.x;  // 64 threads, one wave
  float v = pb[tid];
  #pragma unroll
  for (int m = 1; m < 64; m <<= 1) v += __shfl_xor(v, m, 64);
  if (tid == 0) out[0] = v * (1.0f / 64.0f);
}

extern "C" void kernel_launch(void* const* d_in, const int* in_sizes, int n_in,
                              void* d_out, int out_size, void* d_ws, size_t ws_size,
                              hipStream_t stream) {
  const float* feats = (const float*)d_in[0];
  const int*   tags  = (const int*)d_in[1];
  const int*   lens  = (const int*)d_in[2];
  const float* trans = (const float*)d_in[3];
  float* pb = (float*)d_ws;   // 64 floats of scratch
  crf_forward<<<BB, NTHREADS, 0, stream>>>(feats, tags, lens, trans, pb);
  crf_mean<<<1, 64, 0, stream>>>(pb, (float*)d_out);
}

// Round 4
// 511.094 us; speedup vs baseline: 1.2116x; 1.2116x over previous
//
#include <hip/hip_runtime.h>
#include <math.h>

#define BB 64
#define TT 1024
#define KK 128
#define START_TAG 126
#define NTHREADS 256   // 4 waves; wave w owns rows [32w,32w+32); lane&31 = row, lane>>5 = k-half
#define CS 64          // timesteps of F staged per chunk (32 KB LDS)

typedef float v4f __attribute__((ext_vector_type(4)));

// Deferred-normalization forward recurrence, one barrier per step:
//   u(t) = (u(t-1)·E) ⊙ F(t) × rcp(sigma_slot)        (raw, scale-lagged)
//   sigma_slot <- raw dot at row START (= sum_k u_k, since E[START][:]=1)
//   fwd = M0 + sum_t log(sigma_read(t)) + log(sum_k u_k(L-1))
// The normalizer is read at step start and processed while the dot runs —
// nothing scalar sits on the serial chain. k-split is in-wave (lanes 0-31 vs
// 32-63) so e-reads have only 2 distinct addresses per instr (2-way = free),
// and the k-reduction is a single shfl_xor(32). Rows are wave-owned so the
// e' write is 32 consecutive words (conflict-free).
__global__ __launch_bounds__(NTHREADS) void crf_forward(
    const float* __restrict__ feats,   // [B,T,K]
    const int*   __restrict__ tags,    // [B,T]
    const int*   __restrict__ lens,    // [B]
    const float* __restrict__ trans,   // [K,K]
    float*       __restrict__ out_pb)  // [B]: forward_score - gold_score
{
  __shared__ float Tld[KK][KK + 1];               // raw transitions; reused by gold
  __shared__ __align__(16) float u_two[2][132];   // ping-pong raw alpha; [128] = sigma slot
  __shared__ __align__(16) float maxT_lds[KK];
  __shared__ __align__(16) float Fbuf[CS * KK];   // 32 KB chunk of F = exp(feat+maxT)
  __shared__ float wsum[4];

  const int tid  = threadIdx.x;
  const int b    = blockIdx.x;
  const int w    = tid >> 6;                      // wave 0..3
  const int lane = tid & 63;
  const int h    = lane >> 5;                     // k-half 0/1 (in-wave)
  const int row  = (w << 5) + (lane & 31);        // 0..127
  const int L    = lens[b];
  const float* fb = feats + (size_t)b * TT * KK;

  // ---- stage transitions into LDS ----
  for (int i = tid; i < KK * KK; i += NTHREADS)
    Tld[i >> 7][i & (KK - 1)] = trans[i];
  __syncthreads();

  // ---- row max (half-max + shfl_xor(32)); E half-row into registers ----
  float mT = -INFINITY;
  #pragma unroll
  for (int i = 0; i < 64; ++i) mT = fmaxf(mT, Tld[row][h * 64 + i]);
  mT = fmaxf(mT, __shfl_xor(mT, 32, 64));
  v4f Er4[16];
  #pragma unroll
  for (int i = 0; i < 16; ++i)
    #pragma unroll
    for (int c = 0; c < 4; ++c)
      Er4[i][c] = __expf(Tld[row][h * 64 + 4 * i + c] - mT);
  if (h == 0) maxT_lds[row] = mT;

  // ---- init: u(0) = onehot(START), sigma slot = 1 ----
  if (tid < KK) u_two[0][tid] = (tid == START_TAG) ? 1.0f : 0.0f;
  if (tid == 0) u_two[0][128] = 1.0f;
  const float M0 = fb[START_TAG];
  float Macc = 0.f;                               // wave 0 accumulates log sigma
  __syncthreads();                                // maxT_lds + u visible

  // conversion maxT slice (thread's float4 covers columns (4*tid)&127)
  const float4 mTv = ((const float4*)maxT_lds)[tid & 31];

  // ---- prefetch chunk 0 feats (32 floats/thread, coalesced) ----
  float4 pf[8];
  {
    const float4* src = (const float4*)fb;
    #pragma unroll
    for (int i = 0; i < 8; ++i) pf[i] = src[i * NTHREADS + tid];
  }

  int cur = 0;
  for (int c = 0; c * CS < L; ++c) {
    // convert prefetched feats -> F = exp(feat + maxT)
    float4* Fb4 = (float4*)Fbuf;
    #pragma unroll
    for (int i = 0; i < 8; ++i) {
      float4 v = pf[i];
      float4 o;
      o.x = __expf(v.x + mTv.x); o.y = __expf(v.y + mTv.y);
      o.z = __expf(v.z + mTv.z); o.w = __expf(v.w + mTv.w);
      Fb4[i * NTHREADS + tid] = o;
    }
    if ((c + 1) * CS < TT) {                      // prefetch next chunk
      const float4* src = (const float4*)(fb + (size_t)(c + 1) * CS * KK);
      #pragma unroll
      for (int i = 0; i < 8; ++i) pf[i] = src[i * NTHREADS + tid];
    }
    __syncthreads();                              // Fbuf visible

    const int t0 = (c == 0) ? 1 : c * CS;
    const int t1 = (L < (c + 1) * CS) ? L : (c + 1) * CS;
    for (int t = t0; t < t1; ++t) {
      const float* ucur = u_two[cur];
      float* unxt = u_two[cur ^ 1];
      // off-chain scalars: issue first, consumed only after the dot
      float sig = ucur[128];
      float F   = Fbuf[(t & (CS - 1)) * KK + row];
      // dot over this thread's k-half (2-addr broadcast reads, free 2-way)
      const v4f* e4 = (const v4f*)(ucur + (h << 6));
      v4f a0 = {0,0,0,0}, a1 = {0,0,0,0}, a2 = {0,0,0,0}, a3 = {0,0,0,0};
      #pragma unroll
      for (int i = 0; i < 4; ++i) {
        a0 += e4[4 * i + 0] * Er4[4 * i + 0];
        a1 += e4[4 * i + 1] * Er4[4 * i + 1];
        a2 += e4[4 * i + 2] * Er4[4 * i + 2];
        a3 += e4[4 * i + 3] * Er4[4 * i + 3];
      }
      float r = __builtin_amdgcn_rcpf(sig);       // runs parallel to the dot
      v4f av = (a0 + a1) + (a2 + a3);
      float p = (av[0] + av[1]) + (av[2] + av[3]);
      p += __shfl_xor(p, 32, 64);                 // full 128-wide dot
      if (h == 0) unxt[row] = p * (F * r);
      if (tid == 222) unxt[128] = p;              // raw dot at row 126 = sum_k u_k
      if (tid < 64) Macc += __logf(sig);          // off-chain, wave 0 only
      cur ^= 1;
      __syncthreads();                            // publish u(t)
    }
  }

  // ---- terminal: sum_k u_k(L-1) ----
  float tv = (h == 0) ? u_two[cur][row] : 0.f;
  #pragma unroll
  for (int m = 1; m < 64; m <<= 1) tv += __shfl_xor(tv, m, 64);
  if (lane == 0) wsum[w] = tv;
  __syncthreads();
  float fwd = 0.f;
  if (tid == 0) {
    float s = (wsum[0] + wsum[1]) + (wsum[2] + wsum[3]);
    fwd = M0 + Macc + __logf(s);
  }
  __syncthreads();                                // wsum about to be reused

  // ---- gold score (all threads; Tld still holds raw transitions) ----
  float g = 0.f;
  const int* tg = tags + b * TT;
  for (int t = tid; t < TT; t += NTHREADS) {
    if (t < L)     g += fb[(size_t)t * KK + tg[t]];
    if (t < L - 1) g += Tld[tg[t + 1]][tg[t]];
  }
  #pragma unroll
  for (int m = 1; m < 64; m <<= 1) g += __shfl_xor(g, m, 64);
  if (lane == 0) wsum[w] = g;
  __syncthreads();
  if (tid == 0) {
    float gold = (wsum[0] + wsum[1]) + (wsum[2] + wsum[3]);
    out_pb[b] = fwd - gold;
  }
}

__global__ void crf_mean(const float* __restrict__ pb, float* __restrict__ out) {
  int tid = threadIdx.x;  // 64 threads, one wave
  float v = pb[tid];
  #pragma unroll
  for (int m = 1; m < 64; m <<= 1) v += __shfl_xor(v, m, 64);
  if (tid == 0) out[0] = v * (1.0f / 64.0f);
}

extern "C" void kernel_launch(void* const* d_in, const int* in_sizes, int n_in,
                              void* d_out, int out_size, void* d_ws, size_t ws_size,
                              hipStream_t stream) {
  const float* feats = (const float*)d_in[0];
  const int*   tags  = (const int*)d_in[1];
  const int*   lens  = (const int*)d_in[2];
  const float* trans = (const float*)d_in[3];
  float* pb = (float*)d_ws;   // 64 floats of scratch
  crf_forward<<<BB, NTHREADS, 0, stream>>>(feats, tags, lens, trans, pb);
  crf_mean<<<1, 64, 0, stream>>>(pb, (float*)d_out);
}